// Round 6
// baseline (174.433 us; speedup 1.0000x reference)
//
#include <hip/hip_runtime.h>
#include <hip/hip_bf16.h>
#include <math.h>

#define NPTS   32768

// Workspace float offsets
#define CONV_OFF0 0
#define CONV_OFF1 983040
#define CONV_OFF2 1228800
#define CONV_OFF3 1290240
#define F_RY    1312256   // float[4][48]
#define F_RX    1312448   // float[4][160]
#define F_POOLED 1313088  // float[2][256]
#define F_LWS   1313600   // float[2][4]  (1+lw)
#define F_GSUM  1313608   // float[256]  (column sums of gath)
#define F_PTSUM 1313864   // float[4]
#define F_GATES 1313868   // float[2][128]
#define F_END   1314124
#define F_INBF  1314176   // bf16 channels-last inputs: 5,222,400 bf16 ele
#define INBF_ELE 5222400
#define F_WPACK (F_INBF + INBF_ELE/2)   // 3,925,376 ; bf16 packed lat weights 589,824 ele
#define F_IMGTBF (F_WPACK + 294912)     // 4,220,288 ; bf16 imgt_w 32,768 ele -> ends 4,236,672 (16.95 MB)

typedef short bf16x8 __attribute__((ext_vector_type(8)));
typedef float f32x4  __attribute__((ext_vector_type(4)));

__device__ __forceinline__ float sigm(float z) { return 1.f / (1.f + expf(-z)); }

// ---------------- K0: zero accumulators + resize row/col weight tables -------
__global__ __launch_bounds__(256) void k_tables(float* __restrict__ ws) {
    int gid = blockIdx.x * 256 + threadIdx.x;   // 1024 threads
    for (int i = gid; i < (F_END - F_POOLED); i += 1024) ws[F_POOLED + i] = 0.f;
    for (int idx = gid; idx < 4 * 48; idx += 1024) {
        int l = idx / 48, hh = idx % 48, h = 48 >> l;
        float r = 0.f;
        if (hh < h) {
            float step = (float)(h - 1) / 191.0f;
            for (int Y = 0; Y < 192; ++Y) {
                float ys = step * (float)Y;
                int y0 = (int)ys;
                float f = ys - (float)y0;
                int y1 = min(y0 + 1, h - 1);
                if (y0 == hh) r += 1.f - f;
                if (y1 == hh) r += f;
            }
        }
        ws[F_RY + idx] = r;
    }
    for (int idx = gid; idx < 4 * 160; idx += 1024) {
        int l = idx / 160, xx = idx % 160, w = 160 >> l;
        float r = 0.f;
        if (xx < w) {
            float step = (float)(w - 1) / 639.0f;
            for (int X = 0; X < 640; ++X) {
                float xs = step * (float)X;
                int x0 = (int)xs;
                float f = xs - (float)x0;
                int x1 = min(x0 + 1, w - 1);
                if (x0 == xx) r += 1.f - f;
                if (x1 == xx) r += f;
            }
        }
        ws[F_RX + idx] = r;
    }
}

// ---------------- Kp: pack lat_w + imgt_w fp32 -> bf16 -----------------------
__global__ __launch_bounds__(256) void k_pack_w(const float* __restrict__ lat_w,
                                                const float* __restrict__ imgt_w,
                                                float* __restrict__ ws) {
    int idx = blockIdx.x * 256 + threadIdx.x;
    if (idx < 589824) {
        __hip_bfloat16* wp = (__hip_bfloat16*)(ws + F_WPACK);
        int e = idx & 7; int r = idx >> 3;
        int cm = r & 63; r >>= 6;
        int g = r & 3; r >>= 2;
        int tap = r % 9; r /= 9;
        int chunk = r & 7; int l = r >> 3;
        int ci = chunk * 32 + g * 8 + e;
        float v = lat_w[(((size_t)(l * 64 + cm)) * 256 + ci) * 9 + tap];
        wp[idx] = __float2bfloat16(v);
    } else if (idx < 589824 + 32768) {
        __hip_bfloat16* wb = (__hip_bfloat16*)(ws + F_IMGTBF);
        int i2 = idx - 589824;
        wb[i2] = __float2bfloat16(imgt_w[i2]);
    }
}

// ---------------- Kc: fpn fp32 NCHW -> bf16 channels-last [b][px][ci] --------
__global__ __launch_bounds__(256) void k_chlast(
    const float* __restrict__ f0, const float* __restrict__ f1,
    const float* __restrict__ f2, const float* __restrict__ f3,
    float* __restrict__ ws)
{
    __shared__ __hip_bfloat16 s[64][264];
    __hip_bfloat16* out = (__hip_bfloat16*)(ws + F_INBF);
    int bid = blockIdx.x;
    int l, base, tpb;
    if (bid < 240)      { l = 0; base = 0;   tpb = 120; }
    else if (bid < 300) { l = 1; base = 240; tpb = 30; }
    else if (bid < 316) { l = 2; base = 300; tpb = 8; }
    else                { l = 3; base = 316; tpb = 2; }
    const float* in = (l == 0) ? f0 : (l == 1) ? f1 : (l == 2) ? f2 : f3;
    const int npx_t[4] = {7680, 1920, 480, 120};
    const size_t ob_t[4] = {0, 3932160, 4915200, 5160960};
    int npx = npx_t[l];
    int local = bid - base;
    int b = local / tpb, ti = local % tpb;
    int px0 = ti * 64;
    int t = threadIdx.x;
    int ciq = t >> 6, pxl = t & 63;
    int px = px0 + pxl;
    bool pv = px < npx;
    const float* ip = in + (size_t)b * 256 * npx + px;
    for (int c4 = 0; c4 < 256; c4 += 4) {
        int ci = c4 + ciq;
        float v = pv ? ip[(size_t)ci * npx] : 0.f;
        s[pxl][ci] = __float2bfloat16(v);
    }
    __syncthreads();
    int pr = t >> 5, seg = t & 31;
    __hip_bfloat16* op = out + ob_t[l] + (size_t)b * npx * 256;
    for (int k = 0; k < 8; ++k) {
        int pxw = px0 + pr + k * 8;
        if (pxw < npx) {
            uint4 v = *(const uint4*)&s[pr + 8 * k][seg * 8];
            *(uint4*)&op[(size_t)pxw * 256 + seg * 8] = v;
        }
    }
}

// ---------------- K1: MFMA conv, all levels, fused finalize+pool -------------
__global__ __launch_bounds__(256) void k_conv_mfma(
    float* __restrict__ ws,
    const float* __restrict__ lat_b, const float* __restrict__ lat_s,
    const float* __restrict__ lat_o)
{
    __shared__ __hip_bfloat16 s_a[10][4][18][8];   // [y][g][x][e]
    __shared__ __hip_bfloat16 s_b[9][4][64][8];    // [tap][g][cm][e]
    const __hip_bfloat16* inbf = (const __hip_bfloat16*)(ws + F_INBF);
    const __hip_bfloat16* wp   = (const __hip_bfloat16*)(ws + F_WPACK);

    int bid = blockIdx.x;
    int l, base, tx_n, ty_n;
    if (bid < 120)      { l = 0; base = 0;   tx_n = 10; ty_n = 6; }
    else if (bid < 150) { l = 1; base = 120; tx_n = 5;  ty_n = 3; }
    else if (bid < 162) { l = 2; base = 150; tx_n = 3;  ty_n = 2; }
    else                { l = 3; base = 162; tx_n = 2;  ty_n = 1; }
    const int h_t[4] = {48, 24, 12, 6}, w_t[4] = {160, 80, 40, 20};
    const size_t ib_t[4] = {0, 3932160, 4915200, 5160960};
    const int co_t[4] = {CONV_OFF0, CONV_OFF1, CONV_OFF2, CONV_OFF3};
    int h = h_t[l], w = w_t[l];
    int local = bid - base, tpb = tx_n * ty_n;
    int b = local / tpb, r = local % tpb;
    int tyi = r / tx_n, txi = r % tx_n;
    int gy0 = tyi * 8, gx0 = txi * 16;

    int t = threadIdx.x;
    int wid = t >> 6, lane = t & 63;
    int xl = lane & 15, g = lane >> 4;

    const __hip_bfloat16* ibase = inbf + ib_t[l] + (size_t)b * h * w * 256;
    const __hip_bfloat16* wbase = wp + (size_t)l * 147456;

    f32x4 acc[2][4];
#pragma unroll
    for (int mi = 0; mi < 2; ++mi)
#pragma unroll
        for (int ni = 0; ni < 4; ++ni) acc[mi][ni] = (f32x4){0.f, 0.f, 0.f, 0.f};

    int ay = t / 18, ax = t % 18;
    for (int chunk = 0; chunk < 8; ++chunk) {
        if (t < 180) {
            int gy = gy0 - 1 + ay, gx = gx0 - 1 + ax;
            if (gy >= 0 && gy < h && gx >= 0 && gx < w) {
                const uint4* src = (const uint4*)(ibase + ((size_t)gy * w + gx) * 256 + chunk * 32);
#pragma unroll
                for (int gg = 0; gg < 4; ++gg) *(uint4*)&s_a[ay][gg][ax][0] = src[gg];
            } else {
                uint4 z = make_uint4(0, 0, 0, 0);
#pragma unroll
                for (int gg = 0; gg < 4; ++gg) *(uint4*)&s_a[ay][gg][ax][0] = z;
            }
        }
        {
            const uint4* src = (const uint4*)(wbase + (size_t)chunk * 18432);
            uint4* dst = (uint4*)&s_b[0][0][0][0];
#pragma unroll
            for (int k = 0; k < 9; ++k) dst[t + k * 256] = src[t + k * 256];
        }
        __syncthreads();
#pragma unroll
        for (int tap = 0; tap < 9; ++tap) {
            int ky = tap / 3, kx = tap % 3;
            bf16x8 af[2], bfr[4];
#pragma unroll
            for (int mi = 0; mi < 2; ++mi)
                af[mi] = *(const bf16x8*)&s_a[wid * 2 + mi + ky][g][xl + kx][0];
#pragma unroll
            for (int ni = 0; ni < 4; ++ni)
                bfr[ni] = *(const bf16x8*)&s_b[tap][g][ni * 16 + xl][0];
#pragma unroll
            for (int mi = 0; mi < 2; ++mi)
#pragma unroll
                for (int ni = 0; ni < 4; ++ni)
                    acc[mi][ni] = __builtin_amdgcn_mfma_f32_16x16x32_bf16(
                        af[mi], bfr[ni], acc[mi][ni], 0, 0, 0);
        }
        __syncthreads();
    }

    float bia[4], sca[4], off[4];
#pragma unroll
    for (int ni = 0; ni < 4; ++ni) {
        int cm = ni * 16 + xl;
        bia[ni] = lat_b[l * 64 + cm];
        sca[ni] = lat_s[l * 64 + cm];
        off[ni] = lat_o[l * 64 + cm];
    }
    float wsum[4] = {0.f, 0.f, 0.f, 0.f};
    float* conv = ws + co_t[l];
#pragma unroll
    for (int mi = 0; mi < 2; ++mi) {
        int oy = gy0 + wid * 2 + mi;
        bool yv = oy < h;
        float ry = yv ? ws[F_RY + l * 48 + oy] : 0.f;
#pragma unroll
        for (int j = 0; j < 4; ++j) {
            int ox = gx0 + g * 4 + j;
            bool v = yv && (ox < w);
            float rx = v ? ws[F_RX + l * 160 + ox] : 0.f;
            float rw = ry * rx;
            size_t rowb = (((size_t)b * h + oy) * w + ox) * 64;
#pragma unroll
            for (int ni = 0; ni < 4; ++ni) {
                float val = fmaxf((acc[mi][ni][j] + bia[ni]) * sca[ni] + off[ni], 0.f);
                if (v) {
                    conv[rowb + ni * 16 + xl] = val;
                    wsum[ni] += val * rw;
                }
            }
        }
    }
#pragma unroll
    for (int ni = 0; ni < 4; ++ni) {
        float s = wsum[ni];
        s += __shfl_xor(s, 16);
        s += __shfl_xor(s, 32);
        if (lane < 16) atomicAdd(ws + F_POOLED + b * 256 + l * 64 + ni * 16 + lane, s);
    }
}

// ---------------- K2b: level-attention gates lw -------------------------------
__global__ void k_lw(float* __restrict__ ws,
                     const float* __restrict__ la_w1, const float* __restrict__ la_b1,
                     const float* __restrict__ la_w2, const float* __restrict__ la_b2)
{
    __shared__ float s_hid[2][32];
    int t = threadIdx.x;
    const float invHW = 1.f / (192.f * 640.f);
    if (t < 64) {
        int bb = t >> 5, j = t & 31;
        float acc = la_b1[j];
        const float* P = ws + F_POOLED + bb * 256;
        for (int c = 0; c < 256; ++c) acc += P[c] * invHW * la_w1[j * 256 + c];
        s_hid[bb][j] = fmaxf(acc, 0.f);
    }
    __syncthreads();
    if (t < 8) {
        int bb = t >> 2, l = t & 3;
        float z = la_b2[l];
        for (int j = 0; j < 32; ++j) z += s_hid[bb][j] * la_w2[l * 32 + j];
        ws[F_LWS + bb * 4 + l] = 1.f + sigm(z);
    }
}

// ---------------- Kpt: points column sums ------------------------------------
__global__ __launch_bounds__(256) void k_ptsum(float* __restrict__ ws,
                                               const float* __restrict__ points) {
    __shared__ float s_pt[4][4];
    int t = threadIdx.x, lane = t & 63, wid = t >> 6;
    float sx = 0.f, sy = 0.f, sz = 0.f, si = 0.f;
    int n0 = blockIdx.x * 512;
#pragma unroll
    for (int k = 0; k < 2; ++k) {
        int n = n0 + k * 256 + t;
        const float* P = points + (size_t)n * 5;
        sx += P[1]; sy += P[2]; sz += P[3]; si += P[4];
    }
#pragma unroll
    for (int m = 32; m >= 1; m >>= 1) {
        sx += __shfl_xor(sx, m); sy += __shfl_xor(sy, m);
        sz += __shfl_xor(sz, m); si += __shfl_xor(si, m);
    }
    if (lane == 0) { s_pt[wid][0] = sx; s_pt[wid][1] = sy; s_pt[wid][2] = sz; s_pt[wid][3] = si; }
    __syncthreads();
    if (t < 4) {
        float s = s_pt[0][t] + s_pt[1][t] + s_pt[2][t] + s_pt[3][t];
        atomicAdd(ws + F_PTSUM + t, s);
    }
}

// ---------------- K3a: project+gather -> bf16 gath rows in d_out -------------
// One thread per (point, level); 64 independent contiguous 16B loads/thread.
// gath layout: bf16 [32768][256] occupying d_out's bytes (overwritten later).
__global__ __launch_bounds__(256) void k_gather3(
    float* __restrict__ ws, const float* __restrict__ points,
    const float* __restrict__ calib, float* __restrict__ dout)
{
    int t = threadIdx.x;
    int p = t >> 2, l = t & 3;
    int n = blockIdx.x * 64 + p;
    int b = n >> 14;
    const float* P = points + (size_t)n * 5;
    float px = P[1], py = P[2], pz = P[3];
    const float* C = calib + b * 12;
    float pu = C[0] * px + C[1] * py + C[2]  * pz + C[3];
    float pv = C[4] * px + C[5] * py + C[6]  * pz + C[7];
    float pw = C[8] * px + C[9] * py + C[10] * pz + C[11];
    float zs = fmaxf(pw, 1e-5f);
    float u = pu / zs, v = pv / zs;
    bool on = (u >= 0.f) && (u < 640.f) && (v >= 0.f) && (v < 192.f) && (pw > 1e-5f);
    ushort* orow = (ushort*)dout + (size_t)n * 256 + l * 64;
    if (!on) {
        uint4 z4 = make_uint4(0, 0, 0, 0);
#pragma unroll
        for (int k = 0; k < 8; ++k) ((uint4*)orow)[k] = z4;
        return;
    }
    int ui = min(max((int)u, 0), 639);
    int vi = min(max((int)v, 0), 191);
    int h = 48 >> l, w = 160 >> l;
    float ys = (float)vi * (float)(h - 1) * (1.f / 191.f);
    int y0 = (int)ys; float fy = ys - (float)y0; int y1 = min(y0 + 1, h - 1);
    float xs = (float)ui * (float)(w - 1) * (1.f / 639.f);
    int x0 = (int)xs; float fx = xs - (float)x0; int x1 = min(x0 + 1, w - 1);
    const int co_t[4] = {CONV_OFF0, CONV_OFF1, CONV_OFF2, CONV_OFF3};
    const float* base = ws + co_t[l] + (size_t)b * h * w * 64;
    const float* A00 = base + ((size_t)y0 * w + x0) * 64;
    const float* A01 = base + ((size_t)y0 * w + x1) * 64;
    const float* A10 = base + ((size_t)y1 * w + x0) * 64;
    const float* A11 = base + ((size_t)y1 * w + x1) * 64;
    float sc = ws[F_LWS + b * 4 + l];
    float W00 = (1.f - fy) * (1.f - fx) * sc, W01 = (1.f - fy) * fx * sc;
    float W10 = fy * (1.f - fx) * sc,         W11 = fy * fx * sc;
#pragma unroll
    for (int half = 0; half < 2; ++half) {
        int c0 = half * 32;
        float r[32];
#pragma unroll
        for (int q = 0; q < 8; ++q) {
            float4 a = *(const float4*)(A00 + c0 + q * 4);
            float4 bb = *(const float4*)(A01 + c0 + q * 4);
            float4 c = *(const float4*)(A10 + c0 + q * 4);
            float4 d = *(const float4*)(A11 + c0 + q * 4);
            r[q * 4 + 0] = W00 * a.x + W01 * bb.x + W10 * c.x + W11 * d.x;
            r[q * 4 + 1] = W00 * a.y + W01 * bb.y + W10 * c.y + W11 * d.y;
            r[q * 4 + 2] = W00 * a.z + W01 * bb.z + W10 * c.z + W11 * d.z;
            r[q * 4 + 3] = W00 * a.w + W01 * bb.w + W10 * c.w + W11 * d.w;
        }
        ushort pk[32];
#pragma unroll
        for (int i = 0; i < 32; ++i) {
            __hip_bfloat16 hb = __float2bfloat16(r[i]);
            pk[i] = *(ushort*)&hb;
        }
#pragma unroll
        for (int k = 0; k < 4; ++k)
            *(uint4*)(orow + c0 + k * 8) = *(uint4*)(pk + k * 8);
    }
}

// ---------------- K3g: gath column sums (reads bf16 gath in d_out) -----------
__global__ __launch_bounds__(256) void k_gsum(float* __restrict__ ws,
                                              const float* __restrict__ dout) {
    __shared__ float s_part[8][256];
    const ushort* gath = (const ushort*)dout;
    int t = threadIdx.x;
    int rg = t >> 5, cg = t & 31;
    int r0 = blockIdx.x * 256;
    float s[8] = {0.f, 0.f, 0.f, 0.f, 0.f, 0.f, 0.f, 0.f};
    for (int k = 0; k < 32; ++k) {
        int row = r0 + rg + k * 8;
        uint4 v = *(const uint4*)(gath + (size_t)row * 256 + cg * 8);
        const ushort* e = (const ushort*)&v;
#pragma unroll
        for (int i = 0; i < 8; ++i) {
            unsigned int bits = ((unsigned int)e[i]) << 16;
            s[i] += *(float*)&bits;
        }
    }
#pragma unroll
    for (int i = 0; i < 8; ++i) s_part[rg][cg * 8 + i] = s[i];
    __syncthreads();
    float sum = 0.f;
#pragma unroll
    for (int i = 0; i < 8; ++i) sum += s_part[i][t];
    atomicAdd(ws + F_GSUM + t, sum);
}

// ---------------- K4: SE gates (img_pool from gsum via affine identity) ------
__global__ void k_se(float* __restrict__ ws,
                     const float* __restrict__ imgt_w, const float* __restrict__ imgt_b,
                     const float* __restrict__ imgt_s, const float* __restrict__ imgt_o,
                     const float* __restrict__ pts_w, const float* __restrict__ pts_b,
                     const float* __restrict__ pts_s, const float* __restrict__ pts_o,
                     const float* __restrict__ w1p, const float* __restrict__ w2p,
                     const float* __restrict__ w1i, const float* __restrict__ w2i)
{
    __shared__ float s_cross[256];
    __shared__ float s_hp[128], s_hi[128];
    int t = threadIdx.x;  // 128 threads
    const float invN = 1.f / (float)NPTS;
    float a = 0.f;
    for (int c = 0; c < 256; ++c) a += ws[F_GSUM + c] * imgt_w[(size_t)t * 256 + c];
    s_cross[t] = (a * invN + imgt_b[t]) * imgt_s[t] + imgt_o[t];
    float pp = 0.f;
    for (int k = 0; k < 4; ++k) pp += ws[F_PTSUM + k] * invN * pts_w[t * 4 + k];
    s_cross[128 + t] = (pp + pts_b[t]) * pts_s[t] + pts_o[t];
    __syncthreads();
    float h1 = 0.f, h2 = 0.f;
    for (int c = 0; c < 256; ++c) {
        float cv = s_cross[c];
        h1 += cv * w1p[(size_t)t * 256 + c];
        h2 += cv * w1i[(size_t)t * 256 + c];
    }
    s_hp[t] = fmaxf(h1, 0.f); s_hi[t] = fmaxf(h2, 0.f);
    __syncthreads();
    float g1 = 0.f, g2 = 0.f;
    for (int hh = 0; hh < 128; ++hh) {
        g1 += s_hp[hh] * w2p[(size_t)t * 128 + hh];
        g2 += s_hi[hh] * w2i[(size_t)t * 128 + hh];
    }
    ws[F_GATES + t]       = 1.f + sigm(g1);
    ws[F_GATES + 128 + t] = 1.f + sigm(g2);
}

// ---------------- K5: MFMA img transform + fully fused epilogue --------------
// 512 blocks x 256 thr; stages its own 64 gath rows (bf16, from d_out) into
// LDS, barrier-free MFMA loop, then writes fused fp32 output over same rows.
__global__ __launch_bounds__(256) void k_gemmfuse(
    float* __restrict__ ws, const float* __restrict__ points,
    const float* __restrict__ imgt_b, const float* __restrict__ imgt_s,
    const float* __restrict__ imgt_o,
    const float* __restrict__ pts_w, const float* __restrict__ pts_b,
    const float* __restrict__ pts_s, const float* __restrict__ pts_o,
    float* __restrict__ dout)
{
    __shared__ __hip_bfloat16 s_a[8][4][64][8];   // 32 KB [chunk][g][p][e]
    const ushort* wbf = (const ushort*)(ws + F_IMGTBF);
    int t = threadIdx.x;
    int wid = t >> 6, lane = t & 63, xl = lane & 15, g = lane >> 4;
    int n0 = blockIdx.x * 64;

    // stage: coalesced read of this block's 64 gath rows
    {
        int nl = t >> 2, kq = t & 3;
        const uint4* src = (const uint4*)((const ushort*)dout + (size_t)(n0 + nl) * 256) + kq * 8;
#pragma unroll
        for (int kk = 0; kk < 8; ++kk) {
            uint4 v = src[kk];
            int k = kq * 8 + kk;
            *(uint4*)&s_a[k >> 2][k & 3][nl][0] = v;
        }
    }
    __syncthreads();

    f32x4 acc[8];
#pragma unroll
    for (int ni = 0; ni < 8; ++ni) acc[ni] = (f32x4){0.f, 0.f, 0.f, 0.f};

    for (int chunk = 0; chunk < 8; ++chunk) {
        bf16x8 af = *(const bf16x8*)&s_a[chunk][g][wid * 16 + xl][0];
#pragma unroll
        for (int ni = 0; ni < 8; ++ni) {
            bf16x8 bfr = *(const bf16x8*)(wbf + (size_t)(ni * 16 + xl) * 256 + chunk * 32 + g * 8);
            acc[ni] = __builtin_amdgcn_mfma_f32_16x16x32_bf16(af, bfr, acc[ni], 0, 0, 0);
        }
    }

    // fused epilogue: imgt affine + gates + pts path + relu
    float4 Pt[4];
#pragma unroll
    for (int j = 0; j < 4; ++j) {
        int np = n0 + wid * 16 + g * 4 + j;
        Pt[j] = *(const float4*)(points + (size_t)np * 5 + 1);
    }
#pragma unroll
    for (int ni = 0; ni < 8; ++ni) {
        int o = ni * 16 + xl;
        float ib = imgt_b[o], isc = imgt_s[o], io = imgt_o[o];
        float gp = ws[F_GATES + o], gi = ws[F_GATES + 128 + o];
        float4 pwv = *(const float4*)(pts_w + o * 4);
        float pb = pts_b[o], psc = pts_s[o], po = pts_o[o];
#pragma unroll
        for (int j = 0; j < 4; ++j) {
            int np = n0 + wid * 16 + g * 4 + j;
            float img = (acc[ni][j] + ib) * isc + io;
            float4 pt = Pt[j];
            float pp = (pt.x * pwv.x + pt.y * pwv.y + pt.z * pwv.z + pt.w * pwv.w + pb) * psc + po;
            dout[(size_t)np * 128 + o] = fmaxf(img * gp + pp * gi, 0.f);
        }
    }
}

// ---------------- launch ------------------------------------------------------
extern "C" void kernel_launch(void* const* d_in, const int* in_sizes, int n_in,
                              void* d_out, int out_size, void* d_ws, size_t ws_size,
                              hipStream_t stream)
{
    const float* fpn0 = (const float*)d_in[0];
    const float* fpn1 = (const float*)d_in[1];
    const float* fpn2 = (const float*)d_in[2];
    const float* fpn3 = (const float*)d_in[3];
    const float* points = (const float*)d_in[4];
    const float* calib  = (const float*)d_in[5];
    const float* lat_w  = (const float*)d_in[6];
    const float* lat_b  = (const float*)d_in[7];
    const float* lat_s  = (const float*)d_in[8];
    const float* lat_o  = (const float*)d_in[9];
    const float* pts_w  = (const float*)d_in[10];
    const float* pts_b  = (const float*)d_in[11];
    const float* pts_s  = (const float*)d_in[12];
    const float* pts_o  = (const float*)d_in[13];
    const float* imgt_w = (const float*)d_in[14];
    const float* imgt_b = (const float*)d_in[15];
    const float* imgt_s = (const float*)d_in[16];
    const float* imgt_o = (const float*)d_in[17];
    const float* la_w1  = (const float*)d_in[18];
    const float* la_b1  = (const float*)d_in[19];
    const float* la_w2  = (const float*)d_in[20];
    const float* la_b2  = (const float*)d_in[21];
    const float* se_pt_w1  = (const float*)d_in[22];
    const float* se_pt_w2  = (const float*)d_in[23];
    const float* se_img_w1 = (const float*)d_in[24];
    const float* se_img_w2 = (const float*)d_in[25];

    float* ws = (float*)d_ws;
    float* dout = (float*)d_out;

    k_tables<<<4, 256, 0, stream>>>(ws);
    k_pack_w<<<2433, 256, 0, stream>>>(lat_w, imgt_w, ws);
    k_chlast<<<320, 256, 0, stream>>>(fpn0, fpn1, fpn2, fpn3, ws);
    k_conv_mfma<<<166, 256, 0, stream>>>(ws, lat_b, lat_s, lat_o);
    k_lw<<<1, 64, 0, stream>>>(ws, la_w1, la_b1, la_w2, la_b2);
    k_ptsum<<<64, 256, 0, stream>>>(ws, points);
    k_gather3<<<512, 256, 0, stream>>>(ws, points, calib, dout);
    k_gsum<<<128, 256, 0, stream>>>(ws, dout);
    k_se<<<1, 128, 0, stream>>>(ws, imgt_w, imgt_b, imgt_s, imgt_o,
                                pts_w, pts_b, pts_s, pts_o,
                                se_pt_w1, se_pt_w2, se_img_w1, se_img_w2);
    k_gemmfuse<<<512, 256, 0, stream>>>(ws, points, imgt_b, imgt_s, imgt_o,
                                        pts_w, pts_b, pts_s, pts_o, dout);
}

// Round 7
// 145.729 us; speedup vs baseline: 1.1970x; 1.1970x over previous
//
#include <hip/hip_runtime.h>
#include <hip/hip_bf16.h>
#include <math.h>

#define NPTS   32768

// Workspace float offsets
#define CONV_OFF0 0
#define CONV_OFF1 983040
#define CONV_OFF2 1228800
#define CONV_OFF3 1290240
#define F_RY     1312256   // float[4][48]
#define F_RX     1312448   // float[4][160]
#define F_POOLED 1313088   // float[2][256]  (zeroed; conv atomics)
#define F_GSUM   1313600   // float[256]     (zeroed; gsum atomics)
#define F_LWS    1313856   // float[2][4]    (written by k_lw)
#define F_GATES  1313864   // float[2][128]  (written by k_se)
#define F_PTPART 1314120   // float[64][4]   (fully written by prep/ptsum blocks)
#define F_INBF   1314432   // bf16 channels-last inputs: 5,222,400 bf16 ele
#define INBF_ELE 5222400
#define F_WPACK  (F_INBF + INBF_ELE/2)    // 3,925,632 ; bf16 packed lat weights
#define F_IMGTBF (F_WPACK + 294912)       // 4,220,544 ; bf16 imgt_w -> ends ~16.95 MB

typedef short bf16x8 __attribute__((ext_vector_type(8)));
typedef float f32x4  __attribute__((ext_vector_type(4)));

__device__ __forceinline__ float sigm(float z) { return 1.f / (1.f + expf(-z)); }

// ---------------- K0: merged prep (tables | pack | ptsum | chlast) -----------
// blocks 0-3: zero accum + Ry/Rx tables
// blocks 4-2435: pack lat_w + imgt_w -> bf16
// blocks 2436-2499: points column partial sums (write-only, no atomics)
// blocks 2500-2819: fpn fp32 NCHW -> bf16 channels-last
__global__ __launch_bounds__(256) void k_prep(
    const float* __restrict__ lat_w, const float* __restrict__ imgt_w,
    const float* __restrict__ points,
    const float* __restrict__ f0, const float* __restrict__ f1,
    const float* __restrict__ f2, const float* __restrict__ f3,
    float* __restrict__ ws)
{
    __shared__ __hip_bfloat16 s[64][264];   // used by chlast role
    __shared__ float s_pt[4][4];            // used by ptsum role
    int bid = blockIdx.x, t = threadIdx.x;

    if (bid < 4) {
        int gid = bid * 256 + t;
        for (int i = gid; i < 768; i += 1024) ws[F_POOLED + i] = 0.f;
        for (int idx = gid; idx < 4 * 48; idx += 1024) {
            int l = idx / 48, hh = idx % 48, h = 48 >> l;
            float r = 0.f;
            if (hh < h) {
                float step = (float)(h - 1) / 191.0f;
                for (int Y = 0; Y < 192; ++Y) {
                    float ys = step * (float)Y;
                    int y0 = (int)ys;
                    float f = ys - (float)y0;
                    int y1 = min(y0 + 1, h - 1);
                    if (y0 == hh) r += 1.f - f;
                    if (y1 == hh) r += f;
                }
            }
            ws[F_RY + idx] = r;
        }
        for (int idx = gid; idx < 4 * 160; idx += 1024) {
            int l = idx / 160, xx = idx % 160, w = 160 >> l;
            float r = 0.f;
            if (xx < w) {
                float step = (float)(w - 1) / 639.0f;
                for (int X = 0; X < 640; ++X) {
                    float xs = step * (float)X;
                    int x0 = (int)xs;
                    float f = xs - (float)x0;
                    int x1 = min(x0 + 1, w - 1);
                    if (x0 == xx) r += 1.f - f;
                    if (x1 == xx) r += f;
                }
            }
            ws[F_RX + idx] = r;
        }
    } else if (bid < 2436) {
        int idx = (bid - 4) * 256 + t;
        if (idx < 589824) {
            __hip_bfloat16* wp = (__hip_bfloat16*)(ws + F_WPACK);
            int e = idx & 7; int r = idx >> 3;
            int cm = r & 63; r >>= 6;
            int g = r & 3; r >>= 2;
            int tap = r % 9; r /= 9;
            int chunk = r & 7; int l = r >> 3;
            int ci = chunk * 32 + g * 8 + e;
            float v = lat_w[(((size_t)(l * 64 + cm)) * 256 + ci) * 9 + tap];
            wp[idx] = __float2bfloat16(v);
        } else {
            __hip_bfloat16* wb = (__hip_bfloat16*)(ws + F_IMGTBF);
            int i2 = idx - 589824;
            wb[i2] = __float2bfloat16(imgt_w[i2]);
        }
    } else if (bid < 2500) {
        int pb = bid - 2436;
        int lane = t & 63, wid = t >> 6;
        float sx = 0.f, sy = 0.f, sz = 0.f, si = 0.f;
        int n0 = pb * 512;
#pragma unroll
        for (int k = 0; k < 2; ++k) {
            int n = n0 + k * 256 + t;
            const float* P = points + (size_t)n * 5;
            sx += P[1]; sy += P[2]; sz += P[3]; si += P[4];
        }
#pragma unroll
        for (int m = 32; m >= 1; m >>= 1) {
            sx += __shfl_xor(sx, m); sy += __shfl_xor(sy, m);
            sz += __shfl_xor(sz, m); si += __shfl_xor(si, m);
        }
        if (lane == 0) { s_pt[wid][0] = sx; s_pt[wid][1] = sy; s_pt[wid][2] = sz; s_pt[wid][3] = si; }
        __syncthreads();
        if (t < 4)
            ws[F_PTPART + pb * 4 + t] = s_pt[0][t] + s_pt[1][t] + s_pt[2][t] + s_pt[3][t];
    } else {
        int bid2 = bid - 2500;
        int l, base, tpb;
        if (bid2 < 240)      { l = 0; base = 0;   tpb = 120; }
        else if (bid2 < 300) { l = 1; base = 240; tpb = 30; }
        else if (bid2 < 316) { l = 2; base = 300; tpb = 8; }
        else                 { l = 3; base = 316; tpb = 2; }
        const float* in = (l == 0) ? f0 : (l == 1) ? f1 : (l == 2) ? f2 : f3;
        const int npx_t[4] = {7680, 1920, 480, 120};
        const size_t ob_t[4] = {0, 3932160, 4915200, 5160960};
        int npx = npx_t[l];
        int local = bid2 - base;
        int b = local / tpb, ti = local % tpb;
        int px0 = ti * 64;
        int ciq = t >> 6, pxl = t & 63;
        int px = px0 + pxl;
        bool pv = px < npx;
        __hip_bfloat16* out = (__hip_bfloat16*)(ws + F_INBF);
        const float* ip = in + (size_t)b * 256 * npx + px;
        for (int c4 = 0; c4 < 256; c4 += 4) {
            int ci = c4 + ciq;
            float v = pv ? ip[(size_t)ci * npx] : 0.f;
            s[pxl][ci] = __float2bfloat16(v);
        }
        __syncthreads();
        int pr = t >> 5, seg = t & 31;
        __hip_bfloat16* op = out + ob_t[l] + (size_t)b * npx * 256;
        for (int k = 0; k < 8; ++k) {
            int pxw = px0 + pr + k * 8;
            if (pxw < npx) {
                uint4 v = *(const uint4*)&s[pr + 8 * k][seg * 8];
                *(uint4*)&op[(size_t)pxw * 256 + seg * 8] = v;
            }
        }
    }
}

// ---------------- K1: MFMA conv, 8 waves, K-split halves + LDS reduce --------
// waves 0-3: ci-chunks 0-3; waves 4-7: chunks 4-7; halves merged via s_red.
__global__ __launch_bounds__(512) void k_conv_mfma(
    float* __restrict__ ws,
    const float* __restrict__ lat_b, const float* __restrict__ lat_s,
    const float* __restrict__ lat_o)
{
    __shared__ __hip_bfloat16 s_a[2][10][4][18][8];   // 22.5 KB [half][y][g][x][e]
    __shared__ __hip_bfloat16 s_b[2][9][4][64][8];    // 72 KB   [half][tap][g][cm][e]
    __shared__ float s_red[4][64][32];                // 32 KB
    const __hip_bfloat16* inbf = (const __hip_bfloat16*)(ws + F_INBF);
    const __hip_bfloat16* wp   = (const __hip_bfloat16*)(ws + F_WPACK);

    int bid = blockIdx.x;
    int l, base, tx_n, ty_n;
    if (bid < 120)      { l = 0; base = 0;   tx_n = 10; ty_n = 6; }
    else if (bid < 150) { l = 1; base = 120; tx_n = 5;  ty_n = 3; }
    else if (bid < 162) { l = 2; base = 150; tx_n = 3;  ty_n = 2; }
    else                { l = 3; base = 162; tx_n = 2;  ty_n = 1; }
    const int h_t[4] = {48, 24, 12, 6}, w_t[4] = {160, 80, 40, 20};
    const size_t ib_t[4] = {0, 3932160, 4915200, 5160960};
    const int co_t[4] = {CONV_OFF0, CONV_OFF1, CONV_OFF2, CONV_OFF3};
    int h = h_t[l], w = w_t[l];
    int local = bid - base, tpb = tx_n * ty_n;
    int b = local / tpb, r = local % tpb;
    int tyi = r / tx_n, txi = r % tx_n;
    int gy0 = tyi * 8, gx0 = txi * 16;

    int t = threadIdx.x;
    int half = t >> 8, lt = t & 255;
    int wl = lt >> 6, lane = t & 63;
    int xl = lane & 15, g = lane >> 4;

    const __hip_bfloat16* ibase = inbf + ib_t[l] + (size_t)b * h * w * 256;
    const __hip_bfloat16* wbase = wp + (size_t)l * 147456;

    f32x4 acc[2][4];
#pragma unroll
    for (int mi = 0; mi < 2; ++mi)
#pragma unroll
        for (int ni = 0; ni < 4; ++ni) acc[mi][ni] = (f32x4){0.f, 0.f, 0.f, 0.f};

    int ay = lt / 18, ax = lt % 18;
    for (int c = 0; c < 4; ++c) {
        int chunk = half * 4 + c;
        if (lt < 180) {
            int gy = gy0 - 1 + ay, gx = gx0 - 1 + ax;
            if (gy >= 0 && gy < h && gx >= 0 && gx < w) {
                const uint4* src = (const uint4*)(ibase + ((size_t)gy * w + gx) * 256 + chunk * 32);
#pragma unroll
                for (int gg = 0; gg < 4; ++gg) *(uint4*)&s_a[half][ay][gg][ax][0] = src[gg];
            } else {
                uint4 z = make_uint4(0, 0, 0, 0);
#pragma unroll
                for (int gg = 0; gg < 4; ++gg) *(uint4*)&s_a[half][ay][gg][ax][0] = z;
            }
        }
        {
            const uint4* src = (const uint4*)(wbase + (size_t)chunk * 18432);
            uint4* dst = (uint4*)&s_b[half][0][0][0][0];
#pragma unroll
            for (int k = 0; k < 9; ++k) dst[lt + k * 256] = src[lt + k * 256];
        }
        __syncthreads();
#pragma unroll
        for (int tap = 0; tap < 9; ++tap) {
            int ky = tap / 3, kx = tap % 3;
            bf16x8 af[2], bfr[4];
#pragma unroll
            for (int mi = 0; mi < 2; ++mi)
                af[mi] = *(const bf16x8*)&s_a[half][wl * 2 + mi + ky][g][xl + kx][0];
#pragma unroll
            for (int ni = 0; ni < 4; ++ni)
                bfr[ni] = *(const bf16x8*)&s_b[half][tap][g][ni * 16 + xl][0];
#pragma unroll
            for (int mi = 0; mi < 2; ++mi)
#pragma unroll
                for (int ni = 0; ni < 4; ++ni)
                    acc[mi][ni] = __builtin_amdgcn_mfma_f32_16x16x32_bf16(
                        af[mi], bfr[ni], acc[mi][ni], 0, 0, 0);
        }
        __syncthreads();
    }

    // merge halves
    if (half == 1) {
#pragma unroll
        for (int mi = 0; mi < 2; ++mi)
#pragma unroll
            for (int ni = 0; ni < 4; ++ni)
                *(f32x4*)&s_red[wl][lane][mi * 16 + ni * 4] = acc[mi][ni];
    }
    __syncthreads();
    if (half == 1) return;

#pragma unroll
    for (int mi = 0; mi < 2; ++mi)
#pragma unroll
        for (int ni = 0; ni < 4; ++ni) {
            f32x4 o = *(const f32x4*)&s_red[wl][lane][mi * 16 + ni * 4];
            acc[mi][ni] += o;
        }

    float bia[4], sca[4], off[4];
#pragma unroll
    for (int ni = 0; ni < 4; ++ni) {
        int cm = ni * 16 + xl;
        bia[ni] = lat_b[l * 64 + cm];
        sca[ni] = lat_s[l * 64 + cm];
        off[ni] = lat_o[l * 64 + cm];
    }
    float wsum[4] = {0.f, 0.f, 0.f, 0.f};
    float* conv = ws + co_t[l];
#pragma unroll
    for (int mi = 0; mi < 2; ++mi) {
        int oy = gy0 + wl * 2 + mi;
        bool yv = oy < h;
        float ry = yv ? ws[F_RY + l * 48 + oy] : 0.f;
#pragma unroll
        for (int j = 0; j < 4; ++j) {
            int ox = gx0 + g * 4 + j;
            bool v = yv && (ox < w);
            float rx = v ? ws[F_RX + l * 160 + ox] : 0.f;
            float rw = ry * rx;
            size_t rowb = (((size_t)b * h + oy) * w + ox) * 64;
#pragma unroll
            for (int ni = 0; ni < 4; ++ni) {
                float val = fmaxf((acc[mi][ni][j] + bia[ni]) * sca[ni] + off[ni], 0.f);
                if (v) {
                    conv[rowb + ni * 16 + xl] = val;
                    wsum[ni] += val * rw;
                }
            }
        }
    }
#pragma unroll
    for (int ni = 0; ni < 4; ++ni) {
        float s2 = wsum[ni];
        s2 += __shfl_xor(s2, 16);
        s2 += __shfl_xor(s2, 32);
        if (lane < 16) atomicAdd(ws + F_POOLED + b * 256 + l * 64 + ni * 16 + lane, s2);
    }
}

// ---------------- K2b: level-attention gates lw -------------------------------
__global__ void k_lw(float* __restrict__ ws,
                     const float* __restrict__ la_w1, const float* __restrict__ la_b1,
                     const float* __restrict__ la_w2, const float* __restrict__ la_b2)
{
    __shared__ float s_hid[2][32];
    int t = threadIdx.x;
    const float invHW = 1.f / (192.f * 640.f);
    if (t < 64) {
        int bb = t >> 5, j = t & 31;
        float acc = la_b1[j];
        const float* P = ws + F_POOLED + bb * 256;
        for (int c = 0; c < 256; ++c) acc += P[c] * invHW * la_w1[j * 256 + c];
        s_hid[bb][j] = fmaxf(acc, 0.f);
    }
    __syncthreads();
    if (t < 8) {
        int bb = t >> 2, l = t & 3;
        float z = la_b2[l];
        for (int j = 0; j < 32; ++j) z += s_hid[bb][j] * la_w2[l * 32 + j];
        ws[F_LWS + bb * 4 + l] = 1.f + sigm(z);
    }
}

// ---------------- K3a: project+gather -> bf16 gath rows in d_out -------------
__global__ __launch_bounds__(256) void k_gather3(
    float* __restrict__ ws, const float* __restrict__ points,
    const float* __restrict__ calib, float* __restrict__ dout)
{
    int t = threadIdx.x;
    int p = t >> 2, l = t & 3;
    int n = blockIdx.x * 64 + p;
    int b = n >> 14;
    const float* P = points + (size_t)n * 5;
    float px = P[1], py = P[2], pz = P[3];
    const float* C = calib + b * 12;
    float pu = C[0] * px + C[1] * py + C[2]  * pz + C[3];
    float pv = C[4] * px + C[5] * py + C[6]  * pz + C[7];
    float pw = C[8] * px + C[9] * py + C[10] * pz + C[11];
    float zs = fmaxf(pw, 1e-5f);
    float u = pu / zs, v = pv / zs;
    bool on = (u >= 0.f) && (u < 640.f) && (v >= 0.f) && (v < 192.f) && (pw > 1e-5f);
    ushort* orow = (ushort*)dout + (size_t)n * 256 + l * 64;
    if (!on) {
        uint4 z4 = make_uint4(0, 0, 0, 0);
#pragma unroll
        for (int k = 0; k < 8; ++k) ((uint4*)orow)[k] = z4;
        return;
    }
    int ui = min(max((int)u, 0), 639);
    int vi = min(max((int)v, 0), 191);
    int h = 48 >> l, w = 160 >> l;
    float ys = (float)vi * (float)(h - 1) * (1.f / 191.f);
    int y0 = (int)ys; float fy = ys - (float)y0; int y1 = min(y0 + 1, h - 1);
    float xs = (float)ui * (float)(w - 1) * (1.f / 639.f);
    int x0 = (int)xs; float fx = xs - (float)x0; int x1 = min(x0 + 1, w - 1);
    const int co_t[4] = {CONV_OFF0, CONV_OFF1, CONV_OFF2, CONV_OFF3};
    const float* base = ws + co_t[l] + (size_t)b * h * w * 64;
    const float* A00 = base + ((size_t)y0 * w + x0) * 64;
    const float* A01 = base + ((size_t)y0 * w + x1) * 64;
    const float* A10 = base + ((size_t)y1 * w + x0) * 64;
    const float* A11 = base + ((size_t)y1 * w + x1) * 64;
    float sc = ws[F_LWS + b * 4 + l];
    float W00 = (1.f - fy) * (1.f - fx) * sc, W01 = (1.f - fy) * fx * sc;
    float W10 = fy * (1.f - fx) * sc,         W11 = fy * fx * sc;
#pragma unroll
    for (int half = 0; half < 2; ++half) {
        int c0 = half * 32;
        float r[32];
#pragma unroll
        for (int q = 0; q < 8; ++q) {
            float4 a = *(const float4*)(A00 + c0 + q * 4);
            float4 bb = *(const float4*)(A01 + c0 + q * 4);
            float4 c = *(const float4*)(A10 + c0 + q * 4);
            float4 d = *(const float4*)(A11 + c0 + q * 4);
            r[q * 4 + 0] = W00 * a.x + W01 * bb.x + W10 * c.x + W11 * d.x;
            r[q * 4 + 1] = W00 * a.y + W01 * bb.y + W10 * c.y + W11 * d.y;
            r[q * 4 + 2] = W00 * a.z + W01 * bb.z + W10 * c.z + W11 * d.z;
            r[q * 4 + 3] = W00 * a.w + W01 * bb.w + W10 * c.w + W11 * d.w;
        }
        ushort pk[32];
#pragma unroll
        for (int i = 0; i < 32; ++i) {
            __hip_bfloat16 hb = __float2bfloat16(r[i]);
            pk[i] = *(ushort*)&hb;
        }
#pragma unroll
        for (int k = 0; k < 4; ++k)
            *(uint4*)(orow + c0 + k * 8) = *(uint4*)(pk + k * 8);
    }
}

// ---------------- K3g: gath column sums (reads bf16 gath in d_out) -----------
__global__ __launch_bounds__(256) void k_gsum(float* __restrict__ ws,
                                              const float* __restrict__ dout) {
    __shared__ float s_part[8][256];
    const ushort* gath = (const ushort*)dout;
    int t = threadIdx.x;
    int rg = t >> 5, cg = t & 31;
    int r0 = blockIdx.x * 256;
    float s[8] = {0.f, 0.f, 0.f, 0.f, 0.f, 0.f, 0.f, 0.f};
    for (int k = 0; k < 32; ++k) {
        int row = r0 + rg + k * 8;
        uint4 v = *(const uint4*)(gath + (size_t)row * 256 + cg * 8);
        const ushort* e = (const ushort*)&v;
#pragma unroll
        for (int i = 0; i < 8; ++i) {
            unsigned int bits = ((unsigned int)e[i]) << 16;
            s[i] += *(float*)&bits;
        }
    }
#pragma unroll
    for (int i = 0; i < 8; ++i) s_part[rg][cg * 8 + i] = s[i];
    __syncthreads();
    float sum = 0.f;
#pragma unroll
    for (int i = 0; i < 8; ++i) sum += s_part[i][t];
    atomicAdd(ws + F_GSUM + t, sum);
}

// ---------------- K4: SE gates ------------------------------------------------
__global__ void k_se(float* __restrict__ ws,
                     const float* __restrict__ imgt_w, const float* __restrict__ imgt_b,
                     const float* __restrict__ imgt_s, const float* __restrict__ imgt_o,
                     const float* __restrict__ pts_w, const float* __restrict__ pts_b,
                     const float* __restrict__ pts_s, const float* __restrict__ pts_o,
                     const float* __restrict__ w1p, const float* __restrict__ w2p,
                     const float* __restrict__ w1i, const float* __restrict__ w2i)
{
    __shared__ float s_cross[256];
    __shared__ float s_hp[128], s_hi[128];
    __shared__ float s_pt4[4];
    int t = threadIdx.x;  // 128 threads
    const float invN = 1.f / (float)NPTS;
    if (t < 4) {
        float acc = 0.f;
        for (int bb2 = 0; bb2 < 64; ++bb2) acc += ws[F_PTPART + bb2 * 4 + t];
        s_pt4[t] = acc;
    }
    float a = 0.f;
    for (int c = 0; c < 256; ++c) a += ws[F_GSUM + c] * imgt_w[(size_t)t * 256 + c];
    __syncthreads();
    s_cross[t] = (a * invN + imgt_b[t]) * imgt_s[t] + imgt_o[t];
    float pp = 0.f;
    for (int k = 0; k < 4; ++k) pp += s_pt4[k] * invN * pts_w[t * 4 + k];
    s_cross[128 + t] = (pp + pts_b[t]) * pts_s[t] + pts_o[t];
    __syncthreads();
    float h1 = 0.f, h2 = 0.f;
    for (int c = 0; c < 256; ++c) {
        float cv = s_cross[c];
        h1 += cv * w1p[(size_t)t * 256 + c];
        h2 += cv * w1i[(size_t)t * 256 + c];
    }
    s_hp[t] = fmaxf(h1, 0.f); s_hi[t] = fmaxf(h2, 0.f);
    __syncthreads();
    float g1 = 0.f, g2 = 0.f;
    for (int hh = 0; hh < 128; ++hh) {
        g1 += s_hp[hh] * w2p[(size_t)t * 128 + hh];
        g2 += s_hi[hh] * w2i[(size_t)t * 128 + hh];
    }
    ws[F_GATES + t]       = 1.f + sigm(g1);
    ws[F_GATES + 128 + t] = 1.f + sigm(g2);
}

// ---------------- K5: MFMA img transform + fully fused epilogue --------------
__global__ __launch_bounds__(256) void k_gemmfuse(
    float* __restrict__ ws, const float* __restrict__ points,
    const float* __restrict__ imgt_b, const float* __restrict__ imgt_s,
    const float* __restrict__ imgt_o,
    const float* __restrict__ pts_w, const float* __restrict__ pts_b,
    const float* __restrict__ pts_s, const float* __restrict__ pts_o,
    float* __restrict__ dout)
{
    __shared__ __hip_bfloat16 s_a[8][4][64][8];   // 32 KB [chunk][g][p][e]
    const ushort* wbf = (const ushort*)(ws + F_IMGTBF);
    int t = threadIdx.x;
    int wid = t >> 6, lane = t & 63, xl = lane & 15, g = lane >> 4;
    int n0 = blockIdx.x * 64;

    {
        int nl = t >> 2, kq = t & 3;
        const uint4* src = (const uint4*)((const ushort*)dout + (size_t)(n0 + nl) * 256) + kq * 8;
#pragma unroll
        for (int kk = 0; kk < 8; ++kk) {
            uint4 v = src[kk];
            int k = kq * 8 + kk;
            *(uint4*)&s_a[k >> 2][k & 3][nl][0] = v;
        }
    }
    __syncthreads();

    f32x4 acc[8];
#pragma unroll
    for (int ni = 0; ni < 8; ++ni) acc[ni] = (f32x4){0.f, 0.f, 0.f, 0.f};

    for (int chunk = 0; chunk < 8; ++chunk) {
        bf16x8 af = *(const bf16x8*)&s_a[chunk][g][wid * 16 + xl][0];
#pragma unroll
        for (int ni = 0; ni < 8; ++ni) {
            bf16x8 bfr = *(const bf16x8*)(wbf + (size_t)(ni * 16 + xl) * 256 + chunk * 32 + g * 8);
            acc[ni] = __builtin_amdgcn_mfma_f32_16x16x32_bf16(af, bfr, acc[ni], 0, 0, 0);
        }
    }

    float4 Pt[4];
#pragma unroll
    for (int j = 0; j < 4; ++j) {
        int np = n0 + wid * 16 + g * 4 + j;
        Pt[j] = *(const float4*)(points + (size_t)np * 5 + 1);
    }
#pragma unroll
    for (int ni = 0; ni < 8; ++ni) {
        int o = ni * 16 + xl;
        float ib = imgt_b[o], isc = imgt_s[o], io = imgt_o[o];
        float gp = ws[F_GATES + o], gi = ws[F_GATES + 128 + o];
        float4 pwv = *(const float4*)(pts_w + o * 4);
        float pb = pts_b[o], psc = pts_s[o], po = pts_o[o];
#pragma unroll
        for (int j = 0; j < 4; ++j) {
            int np = n0 + wid * 16 + g * 4 + j;
            float img = (acc[ni][j] + ib) * isc + io;
            float4 pt = Pt[j];
            float pp = (pt.x * pwv.x + pt.y * pwv.y + pt.z * pwv.z + pt.w * pwv.w + pb) * psc + po;
            dout[(size_t)np * 128 + o] = fmaxf(img * gp + pp * gi, 0.f);
        }
    }
}

// ---------------- launch ------------------------------------------------------
extern "C" void kernel_launch(void* const* d_in, const int* in_sizes, int n_in,
                              void* d_out, int out_size, void* d_ws, size_t ws_size,
                              hipStream_t stream)
{
    const float* fpn0 = (const float*)d_in[0];
    const float* fpn1 = (const float*)d_in[1];
    const float* fpn2 = (const float*)d_in[2];
    const float* fpn3 = (const float*)d_in[3];
    const float* points = (const float*)d_in[4];
    const float* calib  = (const float*)d_in[5];
    const float* lat_w  = (const float*)d_in[6];
    const float* lat_b  = (const float*)d_in[7];
    const float* lat_s  = (const float*)d_in[8];
    const float* lat_o  = (const float*)d_in[9];
    const float* pts_w  = (const float*)d_in[10];
    const float* pts_b  = (const float*)d_in[11];
    const float* pts_s  = (const float*)d_in[12];
    const float* pts_o  = (const float*)d_in[13];
    const float* imgt_w = (const float*)d_in[14];
    const float* imgt_b = (const float*)d_in[15];
    const float* imgt_s = (const float*)d_in[16];
    const float* imgt_o = (const float*)d_in[17];
    const float* la_w1  = (const float*)d_in[18];
    const float* la_b1  = (const float*)d_in[19];
    const float* la_w2  = (const float*)d_in[20];
    const float* la_b2  = (const float*)d_in[21];
    const float* se_pt_w1  = (const float*)d_in[22];
    const float* se_pt_w2  = (const float*)d_in[23];
    const float* se_img_w1 = (const float*)d_in[24];
    const float* se_img_w2 = (const float*)d_in[25];

    float* ws = (float*)d_ws;
    float* dout = (float*)d_out;

    k_prep<<<2820, 256, 0, stream>>>(lat_w, imgt_w, points,
                                     fpn0, fpn1, fpn2, fpn3, ws);
    k_conv_mfma<<<166, 512, 0, stream>>>(ws, lat_b, lat_s, lat_o);
    k_lw<<<1, 64, 0, stream>>>(ws, la_w1, la_b1, la_w2, la_b2);
    k_gather3<<<512, 256, 0, stream>>>(ws, points, calib, dout);
    k_gsum<<<128, 256, 0, stream>>>(ws, dout);
    k_se<<<1, 128, 0, stream>>>(ws, imgt_w, imgt_b, imgt_s, imgt_o,
                                pts_w, pts_b, pts_s, pts_o,
                                se_pt_w1, se_pt_w2, se_img_w1, se_img_w2);
    k_gemmfuse<<<512, 256, 0, stream>>>(ws, points, imgt_b, imgt_s, imgt_o,
                                        pts_w, pts_b, pts_s, pts_o, dout);
}

// Round 8
// 140.105 us; speedup vs baseline: 1.2450x; 1.0401x over previous
//
#include <hip/hip_runtime.h>
#include <hip/hip_bf16.h>
#include <math.h>

#define NPTS   32768

// Workspace float offsets
#define CONV_OFF0 0         // conv outputs now bf16 channels-last (capacity unchanged)
#define CONV_OFF1 983040
#define CONV_OFF2 1228800
#define CONV_OFF3 1290240
#define F_RY     1312256   // float[4][48]
#define F_RX     1312448   // float[4][160]
#define F_POOLED 1313088   // float[2][256]  (zeroed; conv atomics)
#define F_GSUM   1313600   // float[256]     (zeroed; gather atomics)
#define F_LWS    1313856   // float[2][4]    (unused now, kept for layout)
#define F_GATES  1313864   // float[2][128]  (written by k_se)
#define F_PTPART 1314120   // float[64][4]   (fully written by prep blocks)
#define F_INBF   1314432   // bf16 channels-last inputs: 5,222,400 bf16 ele
#define INBF_ELE 5222400
#define F_WPACK  (F_INBF + INBF_ELE/2)    // bf16 packed lat weights
#define F_IMGTBF (F_WPACK + 294912)       // bf16 imgt_w -> ends ~16.95 MB

typedef short bf16x8 __attribute__((ext_vector_type(8)));
typedef float f32x4  __attribute__((ext_vector_type(4)));

__device__ __forceinline__ float sigm(float z) { return 1.f / (1.f + expf(-z)); }
__device__ __forceinline__ float bf2f(ushort u) {
    unsigned int b = ((unsigned int)u) << 16;
    return *(float*)&b;
}

// ---------------- K0: merged prep (tables | pack | ptsum | chlast) -----------
__global__ __launch_bounds__(256) void k_prep(
    const float* __restrict__ lat_w, const float* __restrict__ imgt_w,
    const float* __restrict__ points,
    const float* __restrict__ f0, const float* __restrict__ f1,
    const float* __restrict__ f2, const float* __restrict__ f3,
    float* __restrict__ ws)
{
    __shared__ __hip_bfloat16 s[64][264];
    __shared__ float s_pt[4][4];
    int bid = blockIdx.x, t = threadIdx.x;

    if (bid < 4) {
        int gid = bid * 256 + t;
        for (int i = gid; i < 768; i += 1024) ws[F_POOLED + i] = 0.f;
        for (int idx = gid; idx < 4 * 48; idx += 1024) {
            int l = idx / 48, hh = idx % 48, h = 48 >> l;
            float r = 0.f;
            if (hh < h) {
                float step = (float)(h - 1) / 191.0f;
                for (int Y = 0; Y < 192; ++Y) {
                    float ys = step * (float)Y;
                    int y0 = (int)ys;
                    float f = ys - (float)y0;
                    int y1 = min(y0 + 1, h - 1);
                    if (y0 == hh) r += 1.f - f;
                    if (y1 == hh) r += f;
                }
            }
            ws[F_RY + idx] = r;
        }
        for (int idx = gid; idx < 4 * 160; idx += 1024) {
            int l = idx / 160, xx = idx % 160, w = 160 >> l;
            float r = 0.f;
            if (xx < w) {
                float step = (float)(w - 1) / 639.0f;
                for (int X = 0; X < 640; ++X) {
                    float xs = step * (float)X;
                    int x0 = (int)xs;
                    float f = xs - (float)x0;
                    int x1 = min(x0 + 1, w - 1);
                    if (x0 == xx) r += 1.f - f;
                    if (x1 == xx) r += f;
                }
            }
            ws[F_RX + idx] = r;
        }
    } else if (bid < 2436) {
        int idx = (bid - 4) * 256 + t;
        if (idx < 589824) {
            __hip_bfloat16* wp = (__hip_bfloat16*)(ws + F_WPACK);
            int e = idx & 7; int r = idx >> 3;
            int cm = r & 63; r >>= 6;
            int g = r & 3; r >>= 2;
            int tap = r % 9; r /= 9;
            int chunk = r & 7; int l = r >> 3;
            int ci = chunk * 32 + g * 8 + e;
            float v = lat_w[(((size_t)(l * 64 + cm)) * 256 + ci) * 9 + tap];
            wp[idx] = __float2bfloat16(v);
        } else {
            __hip_bfloat16* wb = (__hip_bfloat16*)(ws + F_IMGTBF);
            int i2 = idx - 589824;
            wb[i2] = __float2bfloat16(imgt_w[i2]);
        }
    } else if (bid < 2500) {
        int pb = bid - 2436;
        int lane = t & 63, wid = t >> 6;
        float sx = 0.f, sy = 0.f, sz = 0.f, si = 0.f;
        int n0 = pb * 512;
#pragma unroll
        for (int k = 0; k < 2; ++k) {
            int n = n0 + k * 256 + t;
            const float* P = points + (size_t)n * 5;
            sx += P[1]; sy += P[2]; sz += P[3]; si += P[4];
        }
#pragma unroll
        for (int m = 32; m >= 1; m >>= 1) {
            sx += __shfl_xor(sx, m); sy += __shfl_xor(sy, m);
            sz += __shfl_xor(sz, m); si += __shfl_xor(si, m);
        }
        if (lane == 0) { s_pt[wid][0] = sx; s_pt[wid][1] = sy; s_pt[wid][2] = sz; s_pt[wid][3] = si; }
        __syncthreads();
        if (t < 4)
            ws[F_PTPART + pb * 4 + t] = s_pt[0][t] + s_pt[1][t] + s_pt[2][t] + s_pt[3][t];
    } else {
        int bid2 = bid - 2500;
        int l, base, tpb;
        if (bid2 < 240)      { l = 0; base = 0;   tpb = 120; }
        else if (bid2 < 300) { l = 1; base = 240; tpb = 30; }
        else if (bid2 < 316) { l = 2; base = 300; tpb = 8; }
        else                 { l = 3; base = 316; tpb = 2; }
        const float* in = (l == 0) ? f0 : (l == 1) ? f1 : (l == 2) ? f2 : f3;
        const int npx_t[4] = {7680, 1920, 480, 120};
        const size_t ob_t[4] = {0, 3932160, 4915200, 5160960};
        int npx = npx_t[l];
        int local = bid2 - base;
        int b = local / tpb, ti = local % tpb;
        int px0 = ti * 64;
        int ciq = t >> 6, pxl = t & 63;
        int px = px0 + pxl;
        bool pv = px < npx;
        __hip_bfloat16* out = (__hip_bfloat16*)(ws + F_INBF);
        const float* ip = in + (size_t)b * 256 * npx + px;
        for (int c4 = 0; c4 < 256; c4 += 4) {
            int ci = c4 + ciq;
            float v = pv ? ip[(size_t)ci * npx] : 0.f;
            s[pxl][ci] = __float2bfloat16(v);
        }
        __syncthreads();
        int pr = t >> 5, seg = t & 31;
        __hip_bfloat16* op = out + ob_t[l] + (size_t)b * npx * 256;
        for (int k = 0; k < 8; ++k) {
            int pxw = px0 + pr + k * 8;
            if (pxw < npx) {
                uint4 v = *(const uint4*)&s[pr + 8 * k][seg * 8];
                *(uint4*)&op[(size_t)pxw * 256 + seg * 8] = v;
            }
        }
    }
}

// ---------------- K1: MFMA conv, 8 waves, K-split; bf16 channels-last out ----
__global__ __launch_bounds__(512) void k_conv_mfma(
    float* __restrict__ ws,
    const float* __restrict__ lat_b, const float* __restrict__ lat_s,
    const float* __restrict__ lat_o)
{
    __shared__ __hip_bfloat16 s_a[2][10][4][18][8];
    __shared__ __hip_bfloat16 s_b[2][9][4][64][8];
    __shared__ float s_red[4][64][32];
    const __hip_bfloat16* inbf = (const __hip_bfloat16*)(ws + F_INBF);
    const __hip_bfloat16* wp   = (const __hip_bfloat16*)(ws + F_WPACK);

    int bid = blockIdx.x;
    int l, base, tx_n, ty_n;
    if (bid < 120)      { l = 0; base = 0;   tx_n = 10; ty_n = 6; }
    else if (bid < 150) { l = 1; base = 120; tx_n = 5;  ty_n = 3; }
    else if (bid < 162) { l = 2; base = 150; tx_n = 3;  ty_n = 2; }
    else                { l = 3; base = 162; tx_n = 2;  ty_n = 1; }
    const int h_t[4] = {48, 24, 12, 6}, w_t[4] = {160, 80, 40, 20};
    const size_t ib_t[4] = {0, 3932160, 4915200, 5160960};
    const int co_t[4] = {CONV_OFF0, CONV_OFF1, CONV_OFF2, CONV_OFF3};
    int h = h_t[l], w = w_t[l];
    int local = bid - base, tpb = tx_n * ty_n;
    int b = local / tpb, r = local % tpb;
    int tyi = r / tx_n, txi = r % tx_n;
    int gy0 = tyi * 8, gx0 = txi * 16;

    int t = threadIdx.x;
    int half = t >> 8, lt = t & 255;
    int wl = lt >> 6, lane = t & 63;
    int xl = lane & 15, g = lane >> 4;

    const __hip_bfloat16* ibase = inbf + ib_t[l] + (size_t)b * h * w * 256;
    const __hip_bfloat16* wbase = wp + (size_t)l * 147456;

    f32x4 acc[2][4];
#pragma unroll
    for (int mi = 0; mi < 2; ++mi)
#pragma unroll
        for (int ni = 0; ni < 4; ++ni) acc[mi][ni] = (f32x4){0.f, 0.f, 0.f, 0.f};

    int ay = lt / 18, ax = lt % 18;
    for (int c = 0; c < 4; ++c) {
        int chunk = half * 4 + c;
        if (lt < 180) {
            int gy = gy0 - 1 + ay, gx = gx0 - 1 + ax;
            if (gy >= 0 && gy < h && gx >= 0 && gx < w) {
                const uint4* src = (const uint4*)(ibase + ((size_t)gy * w + gx) * 256 + chunk * 32);
#pragma unroll
                for (int gg = 0; gg < 4; ++gg) *(uint4*)&s_a[half][ay][gg][ax][0] = src[gg];
            } else {
                uint4 z = make_uint4(0, 0, 0, 0);
#pragma unroll
                for (int gg = 0; gg < 4; ++gg) *(uint4*)&s_a[half][ay][gg][ax][0] = z;
            }
        }
        {
            const uint4* src = (const uint4*)(wbase + (size_t)chunk * 18432);
            uint4* dst = (uint4*)&s_b[half][0][0][0][0];
#pragma unroll
            for (int k = 0; k < 9; ++k) dst[lt + k * 256] = src[lt + k * 256];
        }
        __syncthreads();
#pragma unroll
        for (int tap = 0; tap < 9; ++tap) {
            int ky = tap / 3, kx = tap % 3;
            bf16x8 af[2], bfr[4];
#pragma unroll
            for (int mi = 0; mi < 2; ++mi)
                af[mi] = *(const bf16x8*)&s_a[half][wl * 2 + mi + ky][g][xl + kx][0];
#pragma unroll
            for (int ni = 0; ni < 4; ++ni)
                bfr[ni] = *(const bf16x8*)&s_b[half][tap][g][ni * 16 + xl][0];
#pragma unroll
            for (int mi = 0; mi < 2; ++mi)
#pragma unroll
                for (int ni = 0; ni < 4; ++ni)
                    acc[mi][ni] = __builtin_amdgcn_mfma_f32_16x16x32_bf16(
                        af[mi], bfr[ni], acc[mi][ni], 0, 0, 0);
        }
        __syncthreads();
    }

    if (half == 1) {
#pragma unroll
        for (int mi = 0; mi < 2; ++mi)
#pragma unroll
            for (int ni = 0; ni < 4; ++ni)
                *(f32x4*)&s_red[wl][lane][mi * 16 + ni * 4] = acc[mi][ni];
    }
    __syncthreads();
    if (half == 1) return;

#pragma unroll
    for (int mi = 0; mi < 2; ++mi)
#pragma unroll
        for (int ni = 0; ni < 4; ++ni) {
            f32x4 o = *(const f32x4*)&s_red[wl][lane][mi * 16 + ni * 4];
            acc[mi][ni] += o;
        }

    float bia[4], sca[4], off[4];
#pragma unroll
    for (int ni = 0; ni < 4; ++ni) {
        int cm = ni * 16 + xl;
        bia[ni] = lat_b[l * 64 + cm];
        sca[ni] = lat_s[l * 64 + cm];
        off[ni] = lat_o[l * 64 + cm];
    }
    float wsum[4] = {0.f, 0.f, 0.f, 0.f};
    __hip_bfloat16* conv = (__hip_bfloat16*)(ws + co_t[l]);
#pragma unroll
    for (int mi = 0; mi < 2; ++mi) {
        int oy = gy0 + wl * 2 + mi;
        bool yv = oy < h;
        float ry = yv ? ws[F_RY + l * 48 + oy] : 0.f;
#pragma unroll
        for (int j = 0; j < 4; ++j) {
            int ox = gx0 + g * 4 + j;
            bool v = yv && (ox < w);
            float rx = v ? ws[F_RX + l * 160 + ox] : 0.f;
            float rw = ry * rx;
            size_t rowb = (((size_t)b * h + oy) * w + ox) * 64;
#pragma unroll
            for (int ni = 0; ni < 4; ++ni) {
                float val = fmaxf((acc[mi][ni][j] + bia[ni]) * sca[ni] + off[ni], 0.f);
                if (v) {
                    conv[rowb + ni * 16 + xl] = __float2bfloat16(val);
                    wsum[ni] += val * rw;
                }
            }
        }
    }
#pragma unroll
    for (int ni = 0; ni < 4; ++ni) {
        float s2 = wsum[ni];
        s2 += __shfl_xor(s2, 16);
        s2 += __shfl_xor(s2, 32);
        if (lane < 16) atomicAdd(ws + F_POOLED + b * 256 + l * 64 + ni * 16 + lane, s2);
    }
}

// ---------------- K3: project+gather (+inline lw, +gsum) -> bf16 gath --------
// 512 blocks x 256 thr; thread = (point p = t>>2, level l = t&3), 64 ch each.
// lw gates recomputed per block (cheap, removes k_lw); column sums reduced
// via wave shuffles + LDS + 256 atomics/block (removes k_gsum).
__global__ __launch_bounds__(256) void k_gather3(
    float* __restrict__ ws, const float* __restrict__ points,
    const float* __restrict__ calib,
    const float* __restrict__ la_w1, const float* __restrict__ la_b1,
    const float* __restrict__ la_w2, const float* __restrict__ la_b2,
    float* __restrict__ dout)
{
    __shared__ float s_hid[64];
    __shared__ float s_lws[8];
    __shared__ float s_part[4][4][64];   // [wave][l][ch]
    int t = threadIdx.x;
    int p = t >> 2, l = t & 3;
    int wid = t >> 6, lane = t & 63;
    int n = blockIdx.x * 64 + p;
    int b = n >> 14;

    // projection
    const float* P = points + (size_t)n * 5;
    float px = P[1], py = P[2], pz = P[3];
    const float* C = calib + b * 12;
    float pu = C[0] * px + C[1] * py + C[2]  * pz + C[3];
    float pv = C[4] * px + C[5] * py + C[6]  * pz + C[7];
    float pw = C[8] * px + C[9] * py + C[10] * pz + C[11];
    float zs = fmaxf(pw, 1e-5f);
    float u = pu / zs, v = pv / zs;
    bool on = (u >= 0.f) && (u < 640.f) && (v >= 0.f) && (v < 192.f) && (pw > 1e-5f);
    int ui = min(max((int)u, 0), 639);
    int vi = min(max((int)v, 0), 191);

    // inline lw (level-attention gates), redundant per block
    const float invHW = 1.f / (192.f * 640.f);
    if (t < 64) {
        int bb = t >> 5, j = t & 31;
        float acc = la_b1[j];
        const float* PP = ws + F_POOLED + bb * 256;
        const float* Wr = la_w1 + j * 256;
        for (int c = 0; c < 256; c += 4) {
            float4 pc = *(const float4*)(PP + c);
            float4 wc = *(const float4*)(Wr + c);
            acc += (pc.x * wc.x + pc.y * wc.y + pc.z * wc.z + pc.w * wc.w) * invHW;
        }
        s_hid[t] = fmaxf(acc, 0.f);
    }
    __syncthreads();
    if (t < 8) {
        int bb = t >> 2, l2 = t & 3;
        float z = la_b2[l2];
        for (int j = 0; j < 32; ++j) z += s_hid[bb * 32 + j] * la_w2[l2 * 32 + j];
        s_lws[t] = 1.f + sigm(z);
    }
    __syncthreads();

    // bilinear setup (bf16 conv outputs)
    int h = 48 >> l, w = 160 >> l;
    float ys = (float)vi * (float)(h - 1) * (1.f / 191.f);
    int y0 = (int)ys; float fy = ys - (float)y0; int y1 = min(y0 + 1, h - 1);
    float xs = (float)ui * (float)(w - 1) * (1.f / 639.f);
    int x0 = (int)xs; float fx = xs - (float)x0; int x1 = min(x0 + 1, w - 1);
    const int co_t[4] = {CONV_OFF0, CONV_OFF1, CONV_OFF2, CONV_OFF3};
    const ushort* base = (const ushort*)(ws + co_t[l]) + (size_t)b * h * w * 64;
    const ushort* A00 = base + ((size_t)y0 * w + x0) * 64;
    const ushort* A01 = base + ((size_t)y0 * w + x1) * 64;
    const ushort* A10 = base + ((size_t)y1 * w + x0) * 64;
    const ushort* A11 = base + ((size_t)y1 * w + x1) * 64;
    float sc = on ? s_lws[b * 4 + l] : 0.f;   // zero-weights for off-screen
    float W00 = (1.f - fy) * (1.f - fx) * sc, W01 = (1.f - fy) * fx * sc;
    float W10 = fy * (1.f - fx) * sc,         W11 = fy * fx * sc;

    ushort* orow = (ushort*)dout + (size_t)n * 256 + l * 64;
#pragma unroll
    for (int q = 0; q < 8; ++q) {
        uint4 va = *(const uint4*)(A00 + q * 8);
        uint4 vb = *(const uint4*)(A01 + q * 8);
        uint4 vc = *(const uint4*)(A10 + q * 8);
        uint4 vd = *(const uint4*)(A11 + q * 8);
        const ushort* ea = (const ushort*)&va;
        const ushort* eb = (const ushort*)&vb;
        const ushort* ec = (const ushort*)&vc;
        const ushort* ed = (const ushort*)&vd;
        float r[8];
        ushort pk[8];
#pragma unroll
        for (int i = 0; i < 8; ++i) {
            r[i] = W00 * bf2f(ea[i]) + W01 * bf2f(eb[i])
                 + W10 * bf2f(ec[i]) + W11 * bf2f(ed[i]);
            __hip_bfloat16 hb = __float2bfloat16(r[i]);
            pk[i] = *(ushort*)&hb;
        }
        *(uint4*)(orow + q * 8) = *(uint4*)pk;
        // column-sum reduce over the 16 points of this wave (lane bits 2-5)
#pragma unroll
        for (int i = 0; i < 8; ++i) {
            float s = r[i];
            s += __shfl_xor(s, 4);
            s += __shfl_xor(s, 8);
            s += __shfl_xor(s, 16);
            s += __shfl_xor(s, 32);
            r[i] = s;
        }
        if ((lane & 60) == 0) {
#pragma unroll
            for (int i = 0; i < 8; ++i) s_part[wid][l][q * 8 + i] = r[i];
        }
    }
    __syncthreads();
    {
        int c = t, cl = c >> 6, ck = c & 63;
        float s = s_part[0][cl][ck] + s_part[1][cl][ck]
                + s_part[2][cl][ck] + s_part[3][cl][ck];
        atomicAdd(ws + F_GSUM + c, s);
    }
}

// ---------------- K4: SE gates (256 threads, split outputs) ------------------
__global__ __launch_bounds__(256) void k_se(float* __restrict__ ws,
                     const float* __restrict__ imgt_w, const float* __restrict__ imgt_b,
                     const float* __restrict__ imgt_s, const float* __restrict__ imgt_o,
                     const float* __restrict__ pts_w, const float* __restrict__ pts_b,
                     const float* __restrict__ pts_s, const float* __restrict__ pts_o,
                     const float* __restrict__ w1p, const float* __restrict__ w2p,
                     const float* __restrict__ w1i, const float* __restrict__ w2i)
{
    __shared__ float s_cross[256];
    __shared__ float s_h[256];   // [0:128] pt-branch hidden, [128:256] img-branch
    __shared__ float s_pt4[4];
    int t = threadIdx.x;  // 256
    const float invN = 1.f / (float)NPTS;
    if (t < 4) {
        float acc = 0.f;
        for (int bb = 0; bb < 64; ++bb) acc += ws[F_PTPART + bb * 4 + t];
        s_pt4[t] = acc;
    }
    __syncthreads();
    if (t < 128) {
        float a = 0.f;
        const float* Wr = imgt_w + (size_t)t * 256;
        for (int c = 0; c < 256; c += 4) {
            float4 gc = *(const float4*)(ws + F_GSUM + c);
            float4 wc = *(const float4*)(Wr + c);
            a += gc.x * wc.x + gc.y * wc.y + gc.z * wc.z + gc.w * wc.w;
        }
        s_cross[t] = (a * invN + imgt_b[t]) * imgt_s[t] + imgt_o[t];
    } else {
        int o = t - 128;
        float pp = 0.f;
        for (int k = 0; k < 4; ++k) pp += s_pt4[k] * invN * pts_w[o * 4 + k];
        s_cross[128 + o] = (pp + pts_b[o]) * pts_s[o] + pts_o[o];
    }
    __syncthreads();
    {
        int br = t >> 7, o = t & 127;
        const float* W = br ? w1i : w1p;
        const float* Wr = W + (size_t)o * 256;
        float hh = 0.f;
        for (int c = 0; c < 256; c += 4) {
            float4 cc = *(const float4*)(s_cross + c);
            float4 wc = *(const float4*)(Wr + c);
            hh += cc.x * wc.x + cc.y * wc.y + cc.z * wc.z + cc.w * wc.w;
        }
        s_h[t] = fmaxf(hh, 0.f);
    }
    __syncthreads();
    {
        int br = t >> 7, o = t & 127;
        const float* W2 = br ? w2i : w2p;
        const float* Wr = W2 + (size_t)o * 128;
        const float* hb = s_h + br * 128;
        float gg = 0.f;
        for (int c = 0; c < 128; c += 4) {
            float4 hc = *(const float4*)(hb + c);
            float4 wc = *(const float4*)(Wr + c);
            gg += hc.x * wc.x + hc.y * wc.y + hc.z * wc.z + hc.w * wc.w;
        }
        ws[F_GATES + br * 128 + o] = 1.f + sigm(gg);
    }
}

// ---------------- K5: MFMA img transform + fully fused epilogue --------------
__global__ __launch_bounds__(256) void k_gemmfuse(
    float* __restrict__ ws, const float* __restrict__ points,
    const float* __restrict__ imgt_b, const float* __restrict__ imgt_s,
    const float* __restrict__ imgt_o,
    const float* __restrict__ pts_w, const float* __restrict__ pts_b,
    const float* __restrict__ pts_s, const float* __restrict__ pts_o,
    float* __restrict__ dout)
{
    __shared__ __hip_bfloat16 s_a[8][4][64][8];
    const ushort* wbf = (const ushort*)(ws + F_IMGTBF);
    int t = threadIdx.x;
    int wid = t >> 6, lane = t & 63, xl = lane & 15, g = lane >> 4;
    int n0 = blockIdx.x * 64;

    {
        int nl = t >> 2, kq = t & 3;
        const uint4* src = (const uint4*)((const ushort*)dout + (size_t)(n0 + nl) * 256) + kq * 8;
#pragma unroll
        for (int kk = 0; kk < 8; ++kk) {
            uint4 v = src[kk];
            int k = kq * 8 + kk;
            *(uint4*)&s_a[k >> 2][k & 3][nl][0] = v;
        }
    }
    __syncthreads();

    f32x4 acc[8];
#pragma unroll
    for (int ni = 0; ni < 8; ++ni) acc[ni] = (f32x4){0.f, 0.f, 0.f, 0.f};

    for (int chunk = 0; chunk < 8; ++chunk) {
        bf16x8 af = *(const bf16x8*)&s_a[chunk][g][wid * 16 + xl][0];
#pragma unroll
        for (int ni = 0; ni < 8; ++ni) {
            bf16x8 bfr = *(const bf16x8*)(wbf + (size_t)(ni * 16 + xl) * 256 + chunk * 32 + g * 8);
            acc[ni] = __builtin_amdgcn_mfma_f32_16x16x32_bf16(af, bfr, acc[ni], 0, 0, 0);
        }
    }

    float4 Pt[4];
#pragma unroll
    for (int j = 0; j < 4; ++j) {
        int np = n0 + wid * 16 + g * 4 + j;
        Pt[j] = *(const float4*)(points + (size_t)np * 5 + 1);
    }
#pragma unroll
    for (int ni = 0; ni < 8; ++ni) {
        int o = ni * 16 + xl;
        float ib = imgt_b[o], isc = imgt_s[o], io = imgt_o[o];
        float gp = ws[F_GATES + o], gi = ws[F_GATES + 128 + o];
        float4 pwv = *(const float4*)(pts_w + o * 4);
        float pb = pts_b[o], psc = pts_s[o], po = pts_o[o];
#pragma unroll
        for (int j = 0; j < 4; ++j) {
            int np = n0 + wid * 16 + g * 4 + j;
            float img = (acc[ni][j] + ib) * isc + io;
            float4 pt = Pt[j];
            float pp = (pt.x * pwv.x + pt.y * pwv.y + pt.z * pwv.z + pt.w * pwv.w + pb) * psc + po;
            dout[(size_t)np * 128 + o] = fmaxf(img * gp + pp * gi, 0.f);
        }
    }
}

// ---------------- launch ------------------------------------------------------
extern "C" void kernel_launch(void* const* d_in, const int* in_sizes, int n_in,
                              void* d_out, int out_size, void* d_ws, size_t ws_size,
                              hipStream_t stream)
{
    const float* fpn0 = (const float*)d_in[0];
    const float* fpn1 = (const float*)d_in[1];
    const float* fpn2 = (const float*)d_in[2];
    const float* fpn3 = (const float*)d_in[3];
    const float* points = (const float*)d_in[4];
    const float* calib  = (const float*)d_in[5];
    const float* lat_w  = (const float*)d_in[6];
    const float* lat_b  = (const float*)d_in[7];
    const float* lat_s  = (const float*)d_in[8];
    const float* lat_o  = (const float*)d_in[9];
    const float* pts_w  = (const float*)d_in[10];
    const float* pts_b  = (const float*)d_in[11];
    const float* pts_s  = (const float*)d_in[12];
    const float* pts_o  = (const float*)d_in[13];
    const float* imgt_w = (const float*)d_in[14];
    const float* imgt_b = (const float*)d_in[15];
    const float* imgt_s = (const float*)d_in[16];
    const float* imgt_o = (const float*)d_in[17];
    const float* la_w1  = (const float*)d_in[18];
    const float* la_b1  = (const float*)d_in[19];
    const float* la_w2  = (const float*)d_in[20];
    const float* la_b2  = (const float*)d_in[21];
    const float* se_pt_w1  = (const float*)d_in[22];
    const float* se_pt_w2  = (const float*)d_in[23];
    const float* se_img_w1 = (const float*)d_in[24];
    const float* se_img_w2 = (const float*)d_in[25];

    float* ws = (float*)d_ws;
    float* dout = (float*)d_out;

    k_prep<<<2820, 256, 0, stream>>>(lat_w, imgt_w, points,
                                     fpn0, fpn1, fpn2, fpn3, ws);
    k_conv_mfma<<<166, 512, 0, stream>>>(ws, lat_b, lat_s, lat_o);
    k_gather3<<<512, 256, 0, stream>>>(ws, points, calib,
                                       la_w1, la_b1, la_w2, la_b2, dout);
    k_se<<<1, 256, 0, stream>>>(ws, imgt_w, imgt_b, imgt_s, imgt_o,
                                pts_w, pts_b, pts_s, pts_o,
                                se_pt_w1, se_pt_w2, se_img_w1, se_img_w2);
    k_gemmfuse<<<512, 256, 0, stream>>>(ws, points, imgt_b, imgt_s, imgt_o,
                                        pts_w, pts_b, pts_s, pts_o, dout);
}